// Round 18
// baseline (249.858 us; speedup 1.0000x reference)
//
#include <hip/hip_runtime.h>
#include <hip/hip_bf16.h>

#define NN 100000
#define NE 1600000
#define D  128
#define NB 196           // dst buckets of 512 nodes (dst>>9)
#define BSLOT 10240      // fixed slots per bucket region (mean 8192 + 22 sigma)
#define BCHUNK 8192      // edges per binning block
#define NBF (NN / 16)    // 6250 A-fragment groups of 16 nodes

typedef short bf16x8 __attribute__((ext_vector_type(8)));
typedef float f32x4 __attribute__((ext_vector_type(4)));

static __device__ inline unsigned short f2b(float f) {
    __hip_bfloat16 b = __float2bfloat16(f);   // RNE
    unsigned short u;
    __builtin_memcpy(&u, &b, 2);
    return u;
}

// bin edges by dst>>9 into packed 4B entries: (dstLocal9<<17) | src17.
__global__ __launch_bounds__(1024) void bin_scatter(const int* __restrict__ ei,
                                                    int* __restrict__ gcur,
                                                    unsigned* __restrict__ ebuf) {
    __shared__ int hist[NB];
    __shared__ int base_s[NB];
    int chunk0 = blockIdx.x * BCHUNK;
    for (int t = threadIdx.x; t < NB; t += 1024) hist[t] = 0;
    __syncthreads();
    for (int i = 0; i < BCHUNK; i += 1024) {
        int e = chunk0 + i + threadIdx.x;
        if (e < NE) atomicAdd(&hist[ei[NE + e] >> 9], 1);
    }
    __syncthreads();
    for (int t = threadIdx.x; t < NB; t += 1024) {
        base_s[t] = hist[t] ? atomicAdd(&gcur[t], hist[t]) : 0;
        hist[t] = 0;
    }
    __syncthreads();
    for (int i = 0; i < BCHUNK; i += 1024) {
        int e = chunk0 + i + threadIdx.x;
        if (e < NE) {
            int s = ei[e];
            int d = ei[NE + e];
            int b = d >> 9;
            int off = atomicAdd(&hist[b], 1);
            ebuf[(size_t)base_s[b] + off] = ((unsigned)(d & 511) << 17) | (unsigned)s;
        }
    }
}

// One block per 512-node bucket: LDS counts -> scan -> rowbeg/rowend -> col.
// Bucket's col window owned by ONE block on ONE XCD (r11 lesson).
__global__ __launch_bounds__(512) void sort_bucket(
    const unsigned* __restrict__ ebuf, const int* __restrict__ gcur,
    int* __restrict__ rowbeg, int* __restrict__ rowend, int* __restrict__ col)
{
    __shared__ int cnt[512];
    __shared__ int tmp[512];
    __shared__ int cur[512];
    const int b = blockIdx.x;
    const int t = threadIdx.x;
    const int beg = b * BSLOT;
    const int end = gcur[b];
    const int node0 = b << 9;

    cnt[t] = 0;
    __syncthreads();
    for (int j = beg + t; j < end; j += 512)
        atomicAdd(&cnt[ebuf[j] >> 17], 1);
    __syncthreads();

    int v = cnt[t];
    tmp[t] = v;
    __syncthreads();
    for (int off = 1; off < 512; off <<= 1) {
        int tv = (t >= off) ? tmp[t - off] : 0;
        __syncthreads();
        tmp[t] += tv;
        __syncthreads();
    }
    int gpos = beg + (tmp[t] - v);
    if (node0 + t < NN) { rowbeg[node0 + t] = gpos; rowend[node0 + t] = gpos + v; }
    cur[t] = gpos;
    __syncthreads();

    for (int j = beg + t; j < end; j += 512) {
        unsigned p = ebuf[j];
        int pos = atomicAdd(&cur[p >> 17], 1);
        col[pos] = (int)(p & 0x1ffffu);
    }
}

// x -> bf16; 4 weight matrices with MFMA-fragment swizzle Wt[jb][kb][r][8].
// Block 0 inits gcur.
__global__ void conv_all(const float* __restrict__ x,
                         const float* __restrict__ s0, const float* __restrict__ s1,
                         const float* __restrict__ s2, const float* __restrict__ s3,
                         unsigned short* __restrict__ xb,
                         unsigned short* __restrict__ wb,
                         int* __restrict__ gcur) {
    if (blockIdx.x == 0 && threadIdx.x < NB) gcur[threadIdx.x] = threadIdx.x * BSLOT;
    const int xn4 = NN * D / 4;                     // 3.2M
    int idx = blockIdx.x * 256 + threadIdx.x;
    if (idx < xn4) {
        int i = idx * 4;
        float4 v = *(const float4*)(x + i);
        ushort4 o;
        o.x = f2b(v.x); o.y = f2b(v.y); o.z = f2b(v.z); o.w = f2b(v.w);
        *(ushort4*)(xb + i) = o;
    } else if (idx < xn4 + 4 * D * D / 4) {
        int i = (idx - xn4) * 4;                    // [0, 4*D*D)
        const float* srcs[4] = {s0, s1, s2, s3};
        int m = i >> 14;                            // which matrix
        int rem = i & 16383;
        int j = rem >> 7, k = rem & 127;
        float4 v = *(const float4*)(srcs[m] + rem);
        ushort4 o;
        o.x = f2b(v.x); o.y = f2b(v.y); o.z = f2b(v.z); o.w = f2b(v.w);
        unsigned short* dst = wb + m * D * D
            + (((j >> 4) * 16 + (k >> 3)) * 16 + (j & 15)) * 8 + (k & 7);
        *(ushort4*)dst = o;
    }
}

// mean aggregation, uint4/lane gather (r16 inner loop, unchanged numerics).
// Re-blocked: one block = one 16-node fragment group (grid NBF); wave w does
// nodes w*4..w*4+3 serially. Output written in MFMA A-fragment layout
// aggb[nb][kb][r][8] so the GEMM A-load is a contiguous 1KB wave read —
// the 16B-scattered frag writes stay inside this block's 4KB region
// (single block, single XCD — r11 lesson).
__global__ __launch_bounds__(256) void aggregate(const unsigned short* __restrict__ hb,
                                                 const int* __restrict__ rowbeg,
                                                 const int* __restrict__ rowend,
                                                 const int* __restrict__ col,
                                                 unsigned short* __restrict__ aggb) {
    const int nb = blockIdx.x;            // fragment group
    const int node0 = nb * 16;
    const int lane = threadIdx.x & 63;
    const int w    = threadIdx.x >> 6;
    const int grp = lane >> 4;     // edge slot 0..3
    const int gl  = lane & 15;     // uint4 index within the 256B row
    const uint4* hp = (const uint4*)hb;   // 16 uint4 per row

    for (int i = 0; i < 4; ++i) {
        const int node = node0 + w * 4 + i;
        const int beg = rowbeg[node], end = rowend[node];
        float a0 = 0.f, a1 = 0.f, a2 = 0.f, a3 = 0.f;
        float a4 = 0.f, a5 = 0.f, a6 = 0.f, a7 = 0.f;

#define ACC8(V)                                                     \
    {                                                               \
        a0 += __uint_as_float((V).x << 16);                         \
        a1 += __uint_as_float((V).x & 0xffff0000u);                 \
        a2 += __uint_as_float((V).y << 16);                         \
        a3 += __uint_as_float((V).y & 0xffff0000u);                 \
        a4 += __uint_as_float((V).z << 16);                         \
        a5 += __uint_as_float((V).z & 0xffff0000u);                 \
        a6 += __uint_as_float((V).w << 16);                         \
        a7 += __uint_as_float((V).w & 0xffff0000u);                 \
    }
        int j = beg + grp;
        for (; j + 12 < end; j += 16) {       // 16 edges in flight per wave
            int c0 = col[j];
            int c1 = col[j + 4];
            int c2 = col[j + 8];
            int c3 = col[j + 12];
            uint4 v0 = hp[(size_t)c0 * 16 + gl];
            uint4 v1 = hp[(size_t)c1 * 16 + gl];
            uint4 v2 = hp[(size_t)c2 * 16 + gl];
            uint4 v3 = hp[(size_t)c3 * 16 + gl];
            ACC8(v0); ACC8(v1); ACC8(v2); ACC8(v3);
        }
        for (; j < end; j += 4) {
            uint4 v = hp[(size_t)col[j] * 16 + gl];
            ACC8(v);
        }
#undef ACC8

#pragma unroll
        for (int off = 16; off < 64; off <<= 1) {
            a0 += __shfl_xor(a0, off);
            a1 += __shfl_xor(a1, off);
            a2 += __shfl_xor(a2, off);
            a3 += __shfl_xor(a3, off);
            a4 += __shfl_xor(a4, off);
            a5 += __shfl_xor(a5, off);
            a6 += __shfl_xor(a6, off);
            a7 += __shfl_xor(a7, off);
        }

        int deg = end - beg;
        float inv = 1.0f / (float)(deg > 1 ? deg : 1);
        if (grp == 0) {
            uint4 o;
            o.x = (unsigned)f2b(a0 * inv) | ((unsigned)f2b(a1 * inv) << 16);
            o.y = (unsigned)f2b(a2 * inv) | ((unsigned)f2b(a3 * inv) << 16);
            o.z = (unsigned)f2b(a4 * inv) | ((unsigned)f2b(a5 * inv) << 16);
            o.w = (unsigned)f2b(a6 * inv) | ((unsigned)f2b(a7 * inv) << 16);
            // fragment layout: chunk gl of node -> [nb][gl][node&15]
            ((uint4*)aggb)[((size_t)nb * 16 + gl) * 16 + (node & 15)] = o;
        }
    }
}

// out[n][j] = leaky_relu( sum_k agg[n][k]*Wl[j][k] + h[n][k]*Wr[j][k] + b[j], 0.5 )
// MFMA 16x16x32 bf16. A is fragment-swizzled in global (aggregate writes it):
// wave A-load = contiguous 1KB — no sA staging. H staged via LDS (row-major,
// needed row-major for the gather). W fragment-swizzled (conv_all).
template <int OUT_F32>
__global__ __launch_bounds__(256) void sage_gemm_mfma(
    const unsigned short* __restrict__ Ab,   // frag-swizzled [NBF][16][16][8]
    const unsigned short* __restrict__ Hb,   // row-major [NN][128]
    const unsigned short* __restrict__ Wlb,  // swizzled [8][16][16][8]
    const unsigned short* __restrict__ Wrb,
    const float* __restrict__ bias,
    float* __restrict__ outf,
    unsigned short* __restrict__ outb)
{
    __shared__ unsigned short sH[64][136];   // 17.4 KB (272B rows)
    const int tid = threadIdx.x;
    const int block0 = blockIdx.x * 64;

    {
        int i = tid;   // 64 rows x 16 quads = 1024; 4 iters of 256 threads
#pragma unroll
        for (int k = 0; k < 4; ++k, i += 256) {
            int row = i >> 4, c16 = i & 15;
            int grow = block0 + row; if (grow >= NN) grow = NN - 1;
            *(uint4*)(&sH[row][c16 * 8]) = *(const uint4*)(Hb + (size_t)grow * D + c16 * 8);
        }
    }
    __syncthreads();

    const int lane = tid & 63;
    const int wid  = tid >> 6;
    const int r  = lane & 15;
    const int kg = lane >> 4;
    const int rbase = (wid >> 1) * 32;     // 0 or 32
    const int col0  = (wid & 1) * 64;
    const int jb0   = col0 >> 4;
    const int nb0   = min((block0 + rbase) >> 4, NBF - 1);
    const int nb1   = min(((block0 + rbase) >> 4) + 1, NBF - 1);

    float bv[4];
#pragma unroll
    for (int c = 0; c < 4; ++c) bv[c] = bias[col0 + c * 16 + r];

    f32x4 acc[2][4];
#pragma unroll
    for (int m = 0; m < 2; ++m)
#pragma unroll
        for (int c = 0; c < 4; ++c) acc[m][c] = (f32x4){0.f, 0.f, 0.f, 0.f};

#pragma unroll
    for (int ks = 0; ks < 8; ++ks) {
        const int kb = (ks & 3) * 4 + kg;
        bf16x8 a0, a1;
        if (ks < 4) {
            a0 = *(const bf16x8*)(Ab + (((size_t)nb0 * 16 + kb) * 16 + r) * 8);
            a1 = *(const bf16x8*)(Ab + (((size_t)nb1 * 16 + kb) * 16 + r) * 8);
        } else {
            const int kk = (ks & 3) * 32 + kg * 8;
            a0 = *(const bf16x8*)(&sH[rbase + r][kk]);
            a1 = *(const bf16x8*)(&sH[rbase + 16 + r][kk]);
        }
        const unsigned short* W = (ks < 4) ? Wlb : Wrb;
        bf16x8 bw[4];
#pragma unroll
        for (int c = 0; c < 4; ++c)
            bw[c] = *(const bf16x8*)(W + (((jb0 + c) * 16 + kb) * 16 + r) * 8);
#pragma unroll
        for (int c = 0; c < 4; ++c) {
            acc[0][c] = __builtin_amdgcn_mfma_f32_16x16x32_bf16(a0, bw[c], acc[0][c], 0, 0, 0);
            acc[1][c] = __builtin_amdgcn_mfma_f32_16x16x32_bf16(a1, bw[c], acc[1][c], 0, 0, 0);
        }
    }

    // C/D layout: col = c*16 + (lane&15), row = m*16 + (lane>>4)*4 + q   [m89]
#pragma unroll
    for (int m = 0; m < 2; ++m) {
#pragma unroll
        for (int q = 0; q < 4; ++q) {
            int row = block0 + rbase + m * 16 + kg * 4 + q;
            if (row < NN) {
#pragma unroll
                for (int c = 0; c < 4; ++c) {
                    float v = acc[m][c][q] + bv[c];
                    v = v > 0.f ? v : 0.5f * v;
                    int colj = col0 + c * 16 + r;
                    if (OUT_F32) outf[(size_t)row * D + colj] = v;
                    else         outb[(size_t)row * D + colj] = f2b(v);
                }
            }
        }
    }
}

extern "C" void kernel_launch(void* const* d_in, const int* in_sizes, int n_in,
                              void* d_out, int out_size, void* d_ws, size_t ws_size,
                              hipStream_t stream) {
    const float* x   = (const float*)d_in[0];
    const int*   ei  = (const int*)d_in[1];
    const float* W1l = (const float*)d_in[2];
    const float* W1r = (const float*)d_in[3];
    const float* b1  = (const float*)d_in[4];
    const float* W2l = (const float*)d_in[5];
    const float* W2r = (const float*)d_in[6];
    const float* b2  = (const float*)d_in[7];
    float* out = (float*)d_out;

    char* ws = (char*)d_ws;
    size_t off = 0;
    auto alloc = [&](size_t bytes) {
        void* p = ws + off;
        off = (off + bytes + 255) & ~(size_t)255;
        return p;
    };
    int* rowbeg = (int*)alloc((size_t)NN * 4);
    int* rowend = (int*)alloc((size_t)NN * 4);
    int* gcur   = (int*)alloc((NB + 1) * 4);
    int* col    = (int*)alloc((size_t)NB * BSLOT * 4);   // gapped CSR (8 MB)
    unsigned short* xb   = (unsigned short*)alloc((size_t)NN * D * 2);
    unsigned short* aggb = (unsigned short*)alloc((size_t)NN * D * 2);
    unsigned short* h1b  = (unsigned short*)alloc((size_t)NN * D * 2);
    unsigned short* wb   = (unsigned short*)alloc((size_t)4 * D * D * 2);
    unsigned short* w1lb = wb;
    unsigned short* w1rb = wb + D * D;
    unsigned short* w2lb = wb + 2 * D * D;
    unsigned short* w2rb = wb + 3 * D * D;
    // ebuf (8 MB) aliases h1b (25.6 MB): ebuf dead before h1b is written
    unsigned* ebuf = (unsigned*)h1b;

    // ---- conversions (block 0 inits gcur; ordered before bin_scatter) ----
    const int xn4 = NN * D / 4;
    conv_all<<<(xn4 + 4 * D * D / 4 + 255) / 256, 256, 0, stream>>>(
        x, W1l, W1r, W2l, W2r, xb, wb, gcur);

    // ---- CSR build: self-sizing bucket regions, one sort block per bucket ----
    bin_scatter<<<(NE + BCHUNK - 1) / BCHUNK, 1024, 0, stream>>>(ei, gcur, ebuf);
    sort_bucket<<<NB, 512, 0, stream>>>(ebuf, gcur, rowbeg, rowend, col);

    // ---- layer 1 ----
    aggregate<<<NBF, 256, 0, stream>>>(xb, rowbeg, rowend, col, aggb);
    sage_gemm_mfma<0><<<(NN + 63) / 64, 256, 0, stream>>>(aggb, xb, w1lb, w1rb, b1,
                                                          nullptr, h1b);
    // ---- layer 2 ----
    aggregate<<<NBF, 256, 0, stream>>>(h1b, rowbeg, rowend, col, aggb);
    sage_gemm_mfma<1><<<(NN + 63) / 64, 256, 0, stream>>>(aggb, h1b, w2lb, w2rb, b2,
                                                          out, nullptr);
}

// Round 19
// 223.436 us; speedup vs baseline: 1.1183x; 1.1183x over previous
//
#include <hip/hip_runtime.h>
#include <hip/hip_bf16.h>

#define NN 100000
#define NE 1600000
#define D  128
#define NB 196           // dst buckets of 512 nodes (dst>>9)
#define BSLOT 10240      // fixed slots per bucket region (mean 8192 + 22 sigma)
#define BCHUNK 8192      // edges per binning block
#define NBF (NN / 16)    // 6250 A-fragment groups of 16 nodes

typedef short bf16x8 __attribute__((ext_vector_type(8)));
typedef float f32x4 __attribute__((ext_vector_type(4)));

static __device__ inline unsigned short f2b(float f) {
    __hip_bfloat16 b = __float2bfloat16(f);   // RNE
    unsigned short u;
    __builtin_memcpy(&u, &b, 2);
    return u;
}

// bin edges by dst>>9 into packed 4B entries: (dstLocal9<<17) | src17.
__global__ __launch_bounds__(1024) void bin_scatter(const int* __restrict__ ei,
                                                    int* __restrict__ gcur,
                                                    unsigned* __restrict__ ebuf) {
    __shared__ int hist[NB];
    __shared__ int base_s[NB];
    int chunk0 = blockIdx.x * BCHUNK;
    for (int t = threadIdx.x; t < NB; t += 1024) hist[t] = 0;
    __syncthreads();
    for (int i = 0; i < BCHUNK; i += 1024) {
        int e = chunk0 + i + threadIdx.x;
        if (e < NE) atomicAdd(&hist[ei[NE + e] >> 9], 1);
    }
    __syncthreads();
    for (int t = threadIdx.x; t < NB; t += 1024) {
        base_s[t] = hist[t] ? atomicAdd(&gcur[t], hist[t]) : 0;
        hist[t] = 0;
    }
    __syncthreads();
    for (int i = 0; i < BCHUNK; i += 1024) {
        int e = chunk0 + i + threadIdx.x;
        if (e < NE) {
            int s = ei[e];
            int d = ei[NE + e];
            int b = d >> 9;
            int off = atomicAdd(&hist[b], 1);
            ebuf[(size_t)base_s[b] + off] = ((unsigned)(d & 511) << 17) | (unsigned)s;
        }
    }
}

// One block per 512-node bucket: LDS counts -> scan -> rowbeg/rowend -> col.
// Bucket's col window owned by ONE block on ONE XCD (r11 lesson).
__global__ __launch_bounds__(512) void sort_bucket(
    const unsigned* __restrict__ ebuf, const int* __restrict__ gcur,
    int* __restrict__ rowbeg, int* __restrict__ rowend, int* __restrict__ col)
{
    __shared__ int cnt[512];
    __shared__ int tmp[512];
    __shared__ int cur[512];
    const int b = blockIdx.x;
    const int t = threadIdx.x;
    const int beg = b * BSLOT;
    const int end = gcur[b];
    const int node0 = b << 9;

    cnt[t] = 0;
    __syncthreads();
    for (int j = beg + t; j < end; j += 512)
        atomicAdd(&cnt[ebuf[j] >> 17], 1);
    __syncthreads();

    int v = cnt[t];
    tmp[t] = v;
    __syncthreads();
    for (int off = 1; off < 512; off <<= 1) {
        int tv = (t >= off) ? tmp[t - off] : 0;
        __syncthreads();
        tmp[t] += tv;
        __syncthreads();
    }
    int gpos = beg + (tmp[t] - v);
    if (node0 + t < NN) { rowbeg[node0 + t] = gpos; rowend[node0 + t] = gpos + v; }
    cur[t] = gpos;
    __syncthreads();

    for (int j = beg + t; j < end; j += 512) {
        unsigned p = ebuf[j];
        int pos = atomicAdd(&cur[p >> 17], 1);
        col[pos] = (int)(p & 0x1ffffu);
    }
}

// x -> bf16; 4 weight matrices with MFMA-fragment swizzle Wt[jb][kb][r][8].
// Block 0 inits gcur.
__global__ void conv_all(const float* __restrict__ x,
                         const float* __restrict__ s0, const float* __restrict__ s1,
                         const float* __restrict__ s2, const float* __restrict__ s3,
                         unsigned short* __restrict__ xb,
                         unsigned short* __restrict__ wb,
                         int* __restrict__ gcur) {
    if (blockIdx.x == 0 && threadIdx.x < NB) gcur[threadIdx.x] = threadIdx.x * BSLOT;
    const int xn4 = NN * D / 4;                     // 3.2M
    int idx = blockIdx.x * 256 + threadIdx.x;
    if (idx < xn4) {
        int i = idx * 4;
        float4 v = *(const float4*)(x + i);
        ushort4 o;
        o.x = f2b(v.x); o.y = f2b(v.y); o.z = f2b(v.z); o.w = f2b(v.w);
        *(ushort4*)(xb + i) = o;
    } else if (idx < xn4 + 4 * D * D / 4) {
        int i = (idx - xn4) * 4;                    // [0, 4*D*D)
        const float* srcs[4] = {s0, s1, s2, s3};
        int m = i >> 14;                            // which matrix
        int rem = i & 16383;
        int j = rem >> 7, k = rem & 127;
        float4 v = *(const float4*)(srcs[m] + rem);
        ushort4 o;
        o.x = f2b(v.x); o.y = f2b(v.y); o.z = f2b(v.z); o.w = f2b(v.w);
        unsigned short* dst = wb + m * D * D
            + (((j >> 4) * 16 + (k >> 3)) * 16 + (j & 15)) * 8 + (k & 7);
        *(ushort4*)dst = o;
    }
}

// mean aggregation, uint4/lane gather (r16 inner loop, unchanged numerics).
// One block = one 16-node fragment group; wave w does nodes w*4..w*4+3.
// Per-node results buffered in LDS (obuf[16][17], padded -> <=2-way banks);
// one barrier; then the whole 4KB fragment group is stored as a single
// CONTIGUOUS coalesced write (aggb[nb*256 + t]) — full lines, WRITE=payload.
// (r18 lesson: direct frag-layout stores are 16B/line partial writes -> RFO.)
__global__ __launch_bounds__(256) void aggregate(const unsigned short* __restrict__ hb,
                                                 const int* __restrict__ rowbeg,
                                                 const int* __restrict__ rowend,
                                                 const int* __restrict__ col,
                                                 unsigned short* __restrict__ aggb) {
    __shared__ uint4 obuf[16][17];        // [node][chunk gl], padded
    const int nb = blockIdx.x;            // fragment group
    const int node0 = nb * 16;
    const int lane = threadIdx.x & 63;
    const int w    = threadIdx.x >> 6;
    const int grp = lane >> 4;     // edge slot 0..3
    const int gl  = lane & 15;     // uint4 index within the 256B row
    const uint4* hp = (const uint4*)hb;   // 16 uint4 per row

    for (int i = 0; i < 4; ++i) {
        const int node = node0 + w * 4 + i;
        const int beg = rowbeg[node], end = rowend[node];
        float a0 = 0.f, a1 = 0.f, a2 = 0.f, a3 = 0.f;
        float a4 = 0.f, a5 = 0.f, a6 = 0.f, a7 = 0.f;

#define ACC8(V)                                                     \
    {                                                               \
        a0 += __uint_as_float((V).x << 16);                         \
        a1 += __uint_as_float((V).x & 0xffff0000u);                 \
        a2 += __uint_as_float((V).y << 16);                         \
        a3 += __uint_as_float((V).y & 0xffff0000u);                 \
        a4 += __uint_as_float((V).z << 16);                         \
        a5 += __uint_as_float((V).z & 0xffff0000u);                 \
        a6 += __uint_as_float((V).w << 16);                         \
        a7 += __uint_as_float((V).w & 0xffff0000u);                 \
    }
        int j = beg + grp;
        for (; j + 12 < end; j += 16) {       // 16 edges in flight per wave
            int c0 = col[j];
            int c1 = col[j + 4];
            int c2 = col[j + 8];
            int c3 = col[j + 12];
            uint4 v0 = hp[(size_t)c0 * 16 + gl];
            uint4 v1 = hp[(size_t)c1 * 16 + gl];
            uint4 v2 = hp[(size_t)c2 * 16 + gl];
            uint4 v3 = hp[(size_t)c3 * 16 + gl];
            ACC8(v0); ACC8(v1); ACC8(v2); ACC8(v3);
        }
        for (; j < end; j += 4) {
            uint4 v = hp[(size_t)col[j] * 16 + gl];
            ACC8(v);
        }
#undef ACC8

#pragma unroll
        for (int off = 16; off < 64; off <<= 1) {
            a0 += __shfl_xor(a0, off);
            a1 += __shfl_xor(a1, off);
            a2 += __shfl_xor(a2, off);
            a3 += __shfl_xor(a3, off);
            a4 += __shfl_xor(a4, off);
            a5 += __shfl_xor(a5, off);
            a6 += __shfl_xor(a6, off);
            a7 += __shfl_xor(a7, off);
        }

        int deg = end - beg;
        float inv = 1.0f / (float)(deg > 1 ? deg : 1);
        if (grp == 0) {
            uint4 o;
            o.x = (unsigned)f2b(a0 * inv) | ((unsigned)f2b(a1 * inv) << 16);
            o.y = (unsigned)f2b(a2 * inv) | ((unsigned)f2b(a3 * inv) << 16);
            o.z = (unsigned)f2b(a4 * inv) | ((unsigned)f2b(a5 * inv) << 16);
            o.w = (unsigned)f2b(a6 * inv) | ((unsigned)f2b(a7 * inv) << 16);
            obuf[node & 15][gl] = o;
        }
    }
    __syncthreads();

    // coalesced frag-group store: global uint4 idx (nb*16+gl)*16+node = nb*256+t
    const int t = threadIdx.x;
    ((uint4*)aggb)[(size_t)nb * 256 + t] = obuf[t & 15][t >> 4];
}

// out[n][j] = leaky_relu( sum_k agg[n][k]*Wl[j][k] + h[n][k]*Wr[j][k] + b[j], 0.5 )
// MFMA 16x16x32 bf16. A is fragment-swizzled in global (aggregate writes it):
// wave A-load = contiguous 1KB — no sA staging. H staged via LDS (row-major
// needed for the gather). W fragment-swizzled (conv_all).
template <int OUT_F32>
__global__ __launch_bounds__(256) void sage_gemm_mfma(
    const unsigned short* __restrict__ Ab,   // frag-swizzled [NBF][16][16][8]
    const unsigned short* __restrict__ Hb,   // row-major [NN][128]
    const unsigned short* __restrict__ Wlb,  // swizzled [8][16][16][8]
    const unsigned short* __restrict__ Wrb,
    const float* __restrict__ bias,
    float* __restrict__ outf,
    unsigned short* __restrict__ outb)
{
    __shared__ unsigned short sH[64][136];   // 17.4 KB (272B rows)
    const int tid = threadIdx.x;
    const int block0 = blockIdx.x * 64;

    {
        int i = tid;   // 64 rows x 16 quads = 1024; 4 iters of 256 threads
#pragma unroll
        for (int k = 0; k < 4; ++k, i += 256) {
            int row = i >> 4, c16 = i & 15;
            int grow = block0 + row; if (grow >= NN) grow = NN - 1;
            *(uint4*)(&sH[row][c16 * 8]) = *(const uint4*)(Hb + (size_t)grow * D + c16 * 8);
        }
    }
    __syncthreads();

    const int lane = tid & 63;
    const int wid  = tid >> 6;
    const int r  = lane & 15;
    const int kg = lane >> 4;
    const int rbase = (wid >> 1) * 32;     // 0 or 32
    const int col0  = (wid & 1) * 64;
    const int jb0   = col0 >> 4;
    const int nb0   = min((block0 + rbase) >> 4, NBF - 1);
    const int nb1   = min(((block0 + rbase) >> 4) + 1, NBF - 1);

    float bv[4];
#pragma unroll
    for (int c = 0; c < 4; ++c) bv[c] = bias[col0 + c * 16 + r];

    f32x4 acc[2][4];
#pragma unroll
    for (int m = 0; m < 2; ++m)
#pragma unroll
        for (int c = 0; c < 4; ++c) acc[m][c] = (f32x4){0.f, 0.f, 0.f, 0.f};

#pragma unroll
    for (int ks = 0; ks < 8; ++ks) {
        const int kb = (ks & 3) * 4 + kg;
        bf16x8 a0, a1;
        if (ks < 4) {
            a0 = *(const bf16x8*)(Ab + (((size_t)nb0 * 16 + kb) * 16 + r) * 8);
            a1 = *(const bf16x8*)(Ab + (((size_t)nb1 * 16 + kb) * 16 + r) * 8);
        } else {
            const int kk = (ks & 3) * 32 + kg * 8;
            a0 = *(const bf16x8*)(&sH[rbase + r][kk]);
            a1 = *(const bf16x8*)(&sH[rbase + 16 + r][kk]);
        }
        const unsigned short* W = (ks < 4) ? Wlb : Wrb;
        bf16x8 bw[4];
#pragma unroll
        for (int c = 0; c < 4; ++c)
            bw[c] = *(const bf16x8*)(W + (((jb0 + c) * 16 + kb) * 16 + r) * 8);
#pragma unroll
        for (int c = 0; c < 4; ++c) {
            acc[0][c] = __builtin_amdgcn_mfma_f32_16x16x32_bf16(a0, bw[c], acc[0][c], 0, 0, 0);
            acc[1][c] = __builtin_amdgcn_mfma_f32_16x16x32_bf16(a1, bw[c], acc[1][c], 0, 0, 0);
        }
    }

    // C/D layout: col = c*16 + (lane&15), row = m*16 + (lane>>4)*4 + q   [m89]
#pragma unroll
    for (int m = 0; m < 2; ++m) {
#pragma unroll
        for (int q = 0; q < 4; ++q) {
            int row = block0 + rbase + m * 16 + kg * 4 + q;
            if (row < NN) {
#pragma unroll
                for (int c = 0; c < 4; ++c) {
                    float v = acc[m][c][q] + bv[c];
                    v = v > 0.f ? v : 0.5f * v;
                    int colj = col0 + c * 16 + r;
                    if (OUT_F32) outf[(size_t)row * D + colj] = v;
                    else         outb[(size_t)row * D + colj] = f2b(v);
                }
            }
        }
    }
}

extern "C" void kernel_launch(void* const* d_in, const int* in_sizes, int n_in,
                              void* d_out, int out_size, void* d_ws, size_t ws_size,
                              hipStream_t stream) {
    const float* x   = (const float*)d_in[0];
    const int*   ei  = (const int*)d_in[1];
    const float* W1l = (const float*)d_in[2];
    const float* W1r = (const float*)d_in[3];
    const float* b1  = (const float*)d_in[4];
    const float* W2l = (const float*)d_in[5];
    const float* W2r = (const float*)d_in[6];
    const float* b2  = (const float*)d_in[7];
    float* out = (float*)d_out;

    char* ws = (char*)d_ws;
    size_t off = 0;
    auto alloc = [&](size_t bytes) {
        void* p = ws + off;
        off = (off + bytes + 255) & ~(size_t)255;
        return p;
    };
    int* rowbeg = (int*)alloc((size_t)NN * 4);
    int* rowend = (int*)alloc((size_t)NN * 4);
    int* gcur   = (int*)alloc((NB + 1) * 4);
    int* col    = (int*)alloc((size_t)NB * BSLOT * 4);   // gapped CSR (8 MB)
    unsigned short* xb   = (unsigned short*)alloc((size_t)NN * D * 2);
    unsigned short* aggb = (unsigned short*)alloc((size_t)NN * D * 2);
    unsigned short* h1b  = (unsigned short*)alloc((size_t)NN * D * 2);
    unsigned short* wb   = (unsigned short*)alloc((size_t)4 * D * D * 2);
    unsigned short* w1lb = wb;
    unsigned short* w1rb = wb + D * D;
    unsigned short* w2lb = wb + 2 * D * D;
    unsigned short* w2rb = wb + 3 * D * D;
    // ebuf (8 MB) aliases h1b (25.6 MB): ebuf dead before h1b is written
    unsigned* ebuf = (unsigned*)h1b;

    // ---- conversions (block 0 inits gcur; ordered before bin_scatter) ----
    const int xn4 = NN * D / 4;
    conv_all<<<(xn4 + 4 * D * D / 4 + 255) / 256, 256, 0, stream>>>(
        x, W1l, W1r, W2l, W2r, xb, wb, gcur);

    // ---- CSR build: self-sizing bucket regions, one sort block per bucket ----
    bin_scatter<<<(NE + BCHUNK - 1) / BCHUNK, 1024, 0, stream>>>(ei, gcur, ebuf);
    sort_bucket<<<NB, 512, 0, stream>>>(ebuf, gcur, rowbeg, rowend, col);

    // ---- layer 1 ----
    aggregate<<<NBF, 256, 0, stream>>>(xb, rowbeg, rowend, col, aggb);
    sage_gemm_mfma<0><<<(NN + 63) / 64, 256, 0, stream>>>(aggb, xb, w1lb, w1rb, b1,
                                                          nullptr, h1b);
    // ---- layer 2 ----
    aggregate<<<NBF, 256, 0, stream>>>(h1b, rowbeg, rowend, col, aggb);
    sage_gemm_mfma<1><<<(NN + 63) / 64, 256, 0, stream>>>(aggb, h1b, w2lb, w2rb, b2,
                                                          out, nullptr);
}

// Round 20
// 212.810 us; speedup vs baseline: 1.1741x; 1.0499x over previous
//
#include <hip/hip_runtime.h>
#include <hip/hip_bf16.h>

#define NN 100000
#define NE 1600000
#define D  128
#define NB 196           // dst buckets of 512 nodes (dst>>9)
#define BSLOT 10240      // fixed slots per bucket region (mean 8192 + 22 sigma)
#define BCHUNK 8192      // edges per binning block

typedef short bf16x8 __attribute__((ext_vector_type(8)));
typedef float f32x4 __attribute__((ext_vector_type(4)));

static __device__ inline unsigned short f2b(float f) {
    __hip_bfloat16 b = __float2bfloat16(f);   // RNE
    unsigned short u;
    __builtin_memcpy(&u, &b, 2);
    return u;
}

// bin edges by dst>>9 into packed 4B entries: (dstLocal9<<17) | src17.
__global__ __launch_bounds__(1024) void bin_scatter(const int* __restrict__ ei,
                                                    int* __restrict__ gcur,
                                                    unsigned* __restrict__ ebuf) {
    __shared__ int hist[NB];
    __shared__ int base_s[NB];
    int chunk0 = blockIdx.x * BCHUNK;
    for (int t = threadIdx.x; t < NB; t += 1024) hist[t] = 0;
    __syncthreads();
    for (int i = 0; i < BCHUNK; i += 1024) {
        int e = chunk0 + i + threadIdx.x;
        if (e < NE) atomicAdd(&hist[ei[NE + e] >> 9], 1);
    }
    __syncthreads();
    for (int t = threadIdx.x; t < NB; t += 1024) {
        base_s[t] = hist[t] ? atomicAdd(&gcur[t], hist[t]) : 0;
        hist[t] = 0;
    }
    __syncthreads();
    for (int i = 0; i < BCHUNK; i += 1024) {
        int e = chunk0 + i + threadIdx.x;
        if (e < NE) {
            int s = ei[e];
            int d = ei[NE + e];
            int b = d >> 9;
            int off = atomicAdd(&hist[b], 1);
            ebuf[(size_t)base_s[b] + off] = ((unsigned)(d & 511) << 17) | (unsigned)s;
        }
    }
}

// One block per 512-node bucket: LDS counts -> scan -> rowbeg/rowend -> col.
// Bucket's col window owned by ONE block on ONE XCD (r11 lesson).
__global__ __launch_bounds__(512) void sort_bucket(
    const unsigned* __restrict__ ebuf, const int* __restrict__ gcur,
    int* __restrict__ rowbeg, int* __restrict__ rowend, int* __restrict__ col)
{
    __shared__ int cnt[512];
    __shared__ int tmp[512];
    __shared__ int cur[512];
    const int b = blockIdx.x;
    const int t = threadIdx.x;
    const int beg = b * BSLOT;
    const int end = gcur[b];
    const int node0 = b << 9;

    cnt[t] = 0;
    __syncthreads();
    for (int j = beg + t; j < end; j += 512)
        atomicAdd(&cnt[ebuf[j] >> 17], 1);
    __syncthreads();

    int v = cnt[t];
    tmp[t] = v;
    __syncthreads();
    for (int off = 1; off < 512; off <<= 1) {
        int tv = (t >= off) ? tmp[t - off] : 0;
        __syncthreads();
        tmp[t] += tv;
        __syncthreads();
    }
    int gpos = beg + (tmp[t] - v);
    if (node0 + t < NN) { rowbeg[node0 + t] = gpos; rowend[node0 + t] = gpos + v; }
    cur[t] = gpos;
    __syncthreads();

    for (int j = beg + t; j < end; j += 512) {
        unsigned p = ebuf[j];
        int pos = atomicAdd(&cur[p >> 17], 1);
        col[pos] = (int)(p & 0x1ffffu);
    }
}

// x -> bf16; 4 weight matrices with MFMA-fragment swizzle Wt[jb][kb][r][8]:
// a B-fragment load becomes 16 lanes x contiguous 16B = one 256B chunk.
// Block 0 inits gcur.
__global__ void conv_all(const float* __restrict__ x,
                         const float* __restrict__ s0, const float* __restrict__ s1,
                         const float* __restrict__ s2, const float* __restrict__ s3,
                         unsigned short* __restrict__ xb,
                         unsigned short* __restrict__ wb,
                         int* __restrict__ gcur) {
    if (blockIdx.x == 0 && threadIdx.x < NB) gcur[threadIdx.x] = threadIdx.x * BSLOT;
    const int xn4 = NN * D / 4;                     // 3.2M
    int idx = blockIdx.x * 256 + threadIdx.x;
    if (idx < xn4) {
        int i = idx * 4;
        float4 v = *(const float4*)(x + i);
        ushort4 o;
        o.x = f2b(v.x); o.y = f2b(v.y); o.z = f2b(v.z); o.w = f2b(v.w);
        *(ushort4*)(xb + i) = o;
    } else if (idx < xn4 + 4 * D * D / 4) {
        int i = (idx - xn4) * 4;                    // [0, 4*D*D)
        const float* srcs[4] = {s0, s1, s2, s3};
        int m = i >> 14;                            // which matrix
        int rem = i & 16383;
        int j = rem >> 7, k = rem & 127;
        float4 v = *(const float4*)(srcs[m] + rem);
        ushort4 o;
        o.x = f2b(v.x); o.y = f2b(v.y); o.z = f2b(v.z); o.w = f2b(v.w);
        unsigned short* dst = wb + m * D * D
            + (((j >> 4) * 16 + (k >> 3)) * 16 + (j & 15)) * 8 + (k & 7);
        *(ushort4*)dst = o;
    }
}

// mean aggregation over bf16 features — uint4/lane (r16: 59 us, 3.55 TB/s,
// at the L2-fill-path ceiling; structural). 4 groups of 16 lanes, 16 edges
// in flight/wave, shfl_xor(16,32) merge.
__global__ __launch_bounds__(256) void aggregate(const unsigned short* __restrict__ hb,
                                                 const int* __restrict__ rowbeg,
                                                 const int* __restrict__ rowend,
                                                 const int* __restrict__ col,
                                                 unsigned short* __restrict__ aggb) {
    int node = blockIdx.x * 4 + (threadIdx.x >> 6);
    if (node >= NN) return;
    int lane = threadIdx.x & 63;
    int grp = lane >> 4;     // edge slot 0..3
    int gl  = lane & 15;     // uint4 index within the 256B row
    int beg = rowbeg[node], end = rowend[node];
    const uint4* hp = (const uint4*)hb;   // 16 uint4 per row
    float a0 = 0.f, a1 = 0.f, a2 = 0.f, a3 = 0.f;
    float a4 = 0.f, a5 = 0.f, a6 = 0.f, a7 = 0.f;

#define ACC8(V)                                                     \
    {                                                               \
        a0 += __uint_as_float((V).x << 16);                         \
        a1 += __uint_as_float((V).x & 0xffff0000u);                 \
        a2 += __uint_as_float((V).y << 16);                         \
        a3 += __uint_as_float((V).y & 0xffff0000u);                 \
        a4 += __uint_as_float((V).z << 16);                         \
        a5 += __uint_as_float((V).z & 0xffff0000u);                 \
        a6 += __uint_as_float((V).w << 16);                         \
        a7 += __uint_as_float((V).w & 0xffff0000u);                 \
    }

    int j = beg + grp;
    for (; j + 12 < end; j += 16) {       // 16 edges in flight per wave
        int c0 = col[j];
        int c1 = col[j + 4];
        int c2 = col[j + 8];
        int c3 = col[j + 12];
        uint4 v0 = hp[(size_t)c0 * 16 + gl];
        uint4 v1 = hp[(size_t)c1 * 16 + gl];
        uint4 v2 = hp[(size_t)c2 * 16 + gl];
        uint4 v3 = hp[(size_t)c3 * 16 + gl];
        ACC8(v0); ACC8(v1); ACC8(v2); ACC8(v3);
    }
    for (; j < end; j += 4) {
        uint4 v = hp[(size_t)col[j] * 16 + gl];
        ACC8(v);
    }
#undef ACC8

#pragma unroll
    for (int off = 16; off < 64; off <<= 1) {
        a0 += __shfl_xor(a0, off);
        a1 += __shfl_xor(a1, off);
        a2 += __shfl_xor(a2, off);
        a3 += __shfl_xor(a3, off);
        a4 += __shfl_xor(a4, off);
        a5 += __shfl_xor(a5, off);
        a6 += __shfl_xor(a6, off);
        a7 += __shfl_xor(a7, off);
    }

    int deg = end - beg;
    float inv = 1.0f / (float)(deg > 1 ? deg : 1);
    if (grp == 0) {
        uint4 o;
        o.x = (unsigned)f2b(a0 * inv) | ((unsigned)f2b(a1 * inv) << 16);
        o.y = (unsigned)f2b(a2 * inv) | ((unsigned)f2b(a3 * inv) << 16);
        o.z = (unsigned)f2b(a4 * inv) | ((unsigned)f2b(a5 * inv) << 16);
        o.w = (unsigned)f2b(a6 * inv) | ((unsigned)f2b(a7 * inv) << 16);
        ((uint4*)aggb)[(size_t)node * 16 + gl] = o;
    }
}

// out[n][j] = leaky_relu( sum_k agg[n][k]*Wl[j][k] + h[n][k]*Wr[j][k] + b[j], 0.5 )
// MFMA 16x16x32 bf16. Block = 256 thr = 4 waves (2x2), tile 64 rows x 128 cols.
// A/H staged via coalesced uint4 into 272B-padded LDS; W fragment-swizzled
// (conv_all) so each bw load reads one contiguous 256B chunk.
template <int OUT_F32>
__global__ __launch_bounds__(256) void sage_gemm_mfma(
    const unsigned short* __restrict__ Ab,   // [NN][128] aggregated
    const unsigned short* __restrict__ Hb,   // [NN][128] root
    const unsigned short* __restrict__ Wlb,  // swizzled [8][16][16][8]
    const unsigned short* __restrict__ Wrb,
    const float* __restrict__ bias,
    float* __restrict__ outf,
    unsigned short* __restrict__ outb)
{
    __shared__ unsigned short sA[64][136];   // 17.4 KB (272B rows)
    __shared__ unsigned short sH[64][136];
    const int tid = threadIdx.x;
    const int block0 = blockIdx.x * 64;

    {
        int i = tid;   // 64 rows x 16 quads = 1024; 4 iters of 256 threads
#pragma unroll
        for (int k = 0; k < 4; ++k, i += 256) {
            int row = i >> 4, c16 = i & 15;
            int grow = block0 + row; if (grow >= NN) grow = NN - 1;
            *(uint4*)(&sA[row][c16 * 8]) = *(const uint4*)(Ab + (size_t)grow * D + c16 * 8);
            *(uint4*)(&sH[row][c16 * 8]) = *(const uint4*)(Hb + (size_t)grow * D + c16 * 8);
        }
    }
    __syncthreads();

    const int lane = tid & 63;
    const int wid  = tid >> 6;
    const int r  = lane & 15;
    const int kg = lane >> 4;
    const int rbase = (wid >> 1) * 32;     // 0 or 32
    const int col0  = (wid & 1) * 64;
    const int jb0   = col0 >> 4;

    float bv[4];
#pragma unroll
    for (int c = 0; c < 4; ++c) bv[c] = bias[col0 + c * 16 + r];

    f32x4 acc[2][4];
#pragma unroll
    for (int m = 0; m < 2; ++m)
#pragma unroll
        for (int c = 0; c < 4; ++c) acc[m][c] = (f32x4){0.f, 0.f, 0.f, 0.f};

#pragma unroll
    for (int ks = 0; ks < 8; ++ks) {
        const unsigned short (*S)[136] = (ks < 4) ? sA : sH;
        const unsigned short* W = (ks < 4) ? Wlb : Wrb;
        const int kk = (ks & 3) * 32 + kg * 8;
        const int kb = (ks & 3) * 4 + kg;
        bf16x8 a0 = *(const bf16x8*)(&S[rbase + r][kk]);
        bf16x8 a1 = *(const bf16x8*)(&S[rbase + 16 + r][kk]);
        bf16x8 bw[4];
#pragma unroll
        for (int c = 0; c < 4; ++c)
            bw[c] = *(const bf16x8*)(W + (((jb0 + c) * 16 + kb) * 16 + r) * 8);
#pragma unroll
        for (int c = 0; c < 4; ++c) {
            acc[0][c] = __builtin_amdgcn_mfma_f32_16x16x32_bf16(a0, bw[c], acc[0][c], 0, 0, 0);
            acc[1][c] = __builtin_amdgcn_mfma_f32_16x16x32_bf16(a1, bw[c], acc[1][c], 0, 0, 0);
        }
    }

    // C/D layout: col = c*16 + (lane&15), row = m*16 + (lane>>4)*4 + q   [m89]
#pragma unroll
    for (int m = 0; m < 2; ++m) {
#pragma unroll
        for (int q = 0; q < 4; ++q) {
            int row = block0 + rbase + m * 16 + kg * 4 + q;
            if (row < NN) {
#pragma unroll
                for (int c = 0; c < 4; ++c) {
                    float v = acc[m][c][q] + bv[c];
                    v = v > 0.f ? v : 0.5f * v;
                    int colj = col0 + c * 16 + r;
                    if (OUT_F32) outf[(size_t)row * D + colj] = v;
                    else         outb[(size_t)row * D + colj] = f2b(v);
                }
            }
        }
    }
}

extern "C" void kernel_launch(void* const* d_in, const int* in_sizes, int n_in,
                              void* d_out, int out_size, void* d_ws, size_t ws_size,
                              hipStream_t stream) {
    const float* x   = (const float*)d_in[0];
    const int*   ei  = (const int*)d_in[1];
    const float* W1l = (const float*)d_in[2];
    const float* W1r = (const float*)d_in[3];
    const float* b1  = (const float*)d_in[4];
    const float* W2l = (const float*)d_in[5];
    const float* W2r = (const float*)d_in[6];
    const float* b2  = (const float*)d_in[7];
    float* out = (float*)d_out;

    char* ws = (char*)d_ws;
    size_t off = 0;
    auto alloc = [&](size_t bytes) {
        void* p = ws + off;
        off = (off + bytes + 255) & ~(size_t)255;
        return p;
    };
    int* rowbeg = (int*)alloc((size_t)NN * 4);
    int* rowend = (int*)alloc((size_t)NN * 4);
    int* gcur   = (int*)alloc((NB + 1) * 4);
    int* col    = (int*)alloc((size_t)NB * BSLOT * 4);   // gapped CSR (8 MB)
    unsigned short* xb   = (unsigned short*)alloc((size_t)NN * D * 2);
    unsigned short* aggb = (unsigned short*)alloc((size_t)NN * D * 2);
    unsigned short* h1b  = (unsigned short*)alloc((size_t)NN * D * 2);
    unsigned short* wb   = (unsigned short*)alloc((size_t)4 * D * D * 2);
    unsigned short* w1lb = wb;
    unsigned short* w1rb = wb + D * D;
    unsigned short* w2lb = wb + 2 * D * D;
    unsigned short* w2rb = wb + 3 * D * D;
    // ebuf (8 MB) aliases h1b (25.6 MB): ebuf dead before h1b is written
    unsigned* ebuf = (unsigned*)h1b;

    // ---- conversions (block 0 inits gcur; ordered before bin_scatter) ----
    const int xn4 = NN * D / 4;
    conv_all<<<(xn4 + 4 * D * D / 4 + 255) / 256, 256, 0, stream>>>(
        x, W1l, W1r, W2l, W2r, xb, wb, gcur);

    // ---- CSR build: self-sizing bucket regions, one sort block per bucket ----
    bin_scatter<<<(NE + BCHUNK - 1) / BCHUNK, 1024, 0, stream>>>(ei, gcur, ebuf);
    sort_bucket<<<NB, 512, 0, stream>>>(ebuf, gcur, rowbeg, rowend, col);

    // ---- layer 1 ----
    aggregate<<<(NN + 3) / 4, 256, 0, stream>>>(xb, rowbeg, rowend, col, aggb);
    sage_gemm_mfma<0><<<(NN + 63) / 64, 256, 0, stream>>>(aggb, xb, w1lb, w1rb, b1,
                                                          nullptr, h1b);
    // ---- layer 2 ----
    aggregate<<<(NN + 3) / 4, 256, 0, stream>>>(h1b, rowbeg, rowend, col, aggb);
    sage_gemm_mfma<1><<<(NN + 63) / 64, 256, 0, stream>>>(aggb, h1b, w2lb, w2rb, b2,
                                                          out, nullptr);
}